// Round 1
// baseline (1010.108 us; speedup 1.0000x reference)
//
#include <hip/hip_runtime.h>
#include <hip/hip_bf16.h>

#define N_NODES 20000
#define N_EDGES 640000
#define D 128
#define H 256

// MFMA fragment types (guide §3, compile-verified style on gfx950)
using bf16x8 = __attribute__((ext_vector_type(8))) short;
using f32x4  = __attribute__((ext_vector_type(4))) float;

__device__ __forceinline__ unsigned short f2bf(float f) {
  unsigned int u = __float_as_uint(f);
  unsigned int r = u + 0x7fffu + ((u >> 16) & 1u);
  return (unsigned short)(r >> 16);
}

// ---------------- prep: zero agg, nf->bf16, transpose+convert weights ----------------
__global__ __launch_bounds__(256) void prep_kernel(
    const float* __restrict__ nf,
    const float* __restrict__ We1, const float* __restrict__ We2,
    const float* __restrict__ Wn1, const float* __restrict__ Wn2,
    float* __restrict__ agg, unsigned short* __restrict__ nf_bf,
    unsigned short* __restrict__ We1T, unsigned short* __restrict__ We2T,
    unsigned short* __restrict__ Wn1T, unsigned short* __restrict__ Wn2T) {
  int idx = blockIdx.x * 256 + threadIdx.x;
  if (idx < N_NODES * D) {
    agg[idx] = 0.f;
    nf_bf[idx] = f2bf(nf[idx]);
  }
  // weight transposes: W stored [K, N] row-major; WT[n*K + k] = W[k*N + n]
  if (idx < 98304) {                       // We1 [384,256] -> We1T [256,384]
    int n = idx / 384, k = idx % 384;
    We1T[idx] = f2bf(We1[k * 256 + n]);
  } else if (idx < 98304 + 32768) {        // We2 [256,128] -> We2T [128,256]
    int j = idx - 98304; int n = j / 256, k = j % 256;
    We2T[j] = f2bf(We2[k * 128 + n]);
  } else if (idx < 98304 + 32768 + 65536) {// Wn1 [256,256] -> Wn1T [256,256]
    int j = idx - 131072; int n = j / 256, k = j % 256;
    Wn1T[j] = f2bf(Wn1[k * 256 + n]);
  } else if (idx < 229376) {               // Wn2 [256,128] -> Wn2T [128,256]
    int j = idx - 196608; int n = j / 256, k = j % 256;
    Wn2T[j] = f2bf(Wn2[k * 128 + n]);
  }
}

// ---------------- edge kernel: 64 edges/block, fused 2-layer MLP + scatter-add ----------------
#define AS 392   // em_in LDS row stride (bf16 elems): 384 + 8 pad -> uniform bank spread
#define HS 264   // h LDS row stride: 256 + 8 pad

__global__ __launch_bounds__(256, 3) void edge_kernel(
    const float* __restrict__ ef, const unsigned short* __restrict__ nf_bf,
    const int* __restrict__ src, const int* __restrict__ dst,
    const unsigned short* __restrict__ We1T, const float* __restrict__ be1,
    const unsigned short* __restrict__ We2T, const float* __restrict__ be2,
    float* __restrict__ out_ef, float* __restrict__ agg) {
  __shared__ unsigned short smem[64 * AS];   // 50176 B; h overlaid after barrier
  unsigned short* hbuf = smem;

  const int tid  = threadIdx.x;
  const int lane = tid & 63;
  const int wave = tid >> 6;
  const int ln15 = lane & 15;
  const int q    = lane >> 4;
  const int e0   = blockIdx.x * 64;

  // ---- stage em_in = [ef | nf[src] | nf[dst]] as bf16 ----
  {
    const float4* ef4 = (const float4*)ef;
#pragma unroll
    for (int i = 0; i < 8; i++) {
      int flat = tid + 256 * i;             // 2048 float4 tasks
      int row = flat >> 5, c4 = flat & 31;
      float4 v = ef4[(size_t)(e0 + row) * 32 + c4];
      ushort4 o = { f2bf(v.x), f2bf(v.y), f2bf(v.z), f2bf(v.w) };
      *(ushort4*)&smem[row * AS + c4 * 4] = o;
    }
#pragma unroll
    for (int i = 0; i < 4; i++) {
      int flat = tid + 256 * i;             // 1024 16B tasks per side
      int row = flat >> 4, seg = flat & 15;
      int e = e0 + row;
      int s = src[e];
      int d = dst[e];
      *(uint4*)&smem[row * AS + 128 + seg * 8] =
          *(const uint4*)&nf_bf[(size_t)s * 128 + seg * 8];
      *(uint4*)&smem[row * AS + 256 + seg * 8] =
          *(const uint4*)&nf_bf[(size_t)d * 128 + seg * 8];
    }
  }
  __syncthreads();

  // ---- layer 1: h[64,256] = relu(em_in @ We1 + be1); wave w owns cols [64w,64w+64) ----
  const int nb1 = wave * 64;
  f32x4 acc[4][4] = {};
  float bias1[4];
#pragma unroll
  for (int nt = 0; nt < 4; nt++) bias1[nt] = be1[nb1 + nt * 16 + ln15];

#pragma unroll
  for (int ks = 0; ks < 12; ks++) {
    const int kc = ks * 32 + q * 8;
    bf16x8 a[4], b[4];
#pragma unroll
    for (int mt = 0; mt < 4; mt++)
      a[mt] = *(const bf16x8*)&smem[(mt * 16 + ln15) * AS + kc];
#pragma unroll
    for (int nt = 0; nt < 4; nt++)
      b[nt] = *(const bf16x8*)&We1T[(size_t)(nb1 + nt * 16 + ln15) * 384 + kc];
#pragma unroll
    for (int mt = 0; mt < 4; mt++)
#pragma unroll
      for (int nt = 0; nt < 4; nt++)
        acc[mt][nt] = __builtin_amdgcn_mfma_f32_16x16x32_bf16(a[mt], b[nt], acc[mt][nt], 0, 0, 0);
  }
  __syncthreads();   // all A reads done; safe to overlay h

  // C/D layout: col = lane&15, row = q*4 + reg
#pragma unroll
  for (int mt = 0; mt < 4; mt++)
#pragma unroll
    for (int nt = 0; nt < 4; nt++)
#pragma unroll
      for (int r = 0; r < 4; r++) {
        float v = acc[mt][nt][r] + bias1[nt];
        v = v > 0.f ? v : 0.f;
        hbuf[(mt * 16 + q * 4 + r) * HS + nb1 + nt * 16 + ln15] = f2bf(v);
      }
  __syncthreads();

  // ---- layer 2: out[64,128] = h @ We2 + be2; wave w owns cols [32w,32w+32) ----
  const int nb2 = wave * 32;
  f32x4 acc2[4][2] = {};
  float bias2[2];
#pragma unroll
  for (int nt = 0; nt < 2; nt++) bias2[nt] = be2[nb2 + nt * 16 + ln15];

#pragma unroll
  for (int ks = 0; ks < 8; ks++) {
    const int kc = ks * 32 + q * 8;
    bf16x8 a2[4], b2[2];
#pragma unroll
    for (int mt = 0; mt < 4; mt++)
      a2[mt] = *(const bf16x8*)&hbuf[(mt * 16 + ln15) * HS + kc];
#pragma unroll
    for (int nt = 0; nt < 2; nt++)
      b2[nt] = *(const bf16x8*)&We2T[(size_t)(nb2 + nt * 16 + ln15) * 256 + kc];
#pragma unroll
    for (int mt = 0; mt < 4; mt++)
#pragma unroll
      for (int nt = 0; nt < 2; nt++)
        acc2[mt][nt] = __builtin_amdgcn_mfma_f32_16x16x32_bf16(a2[mt], b2[nt], acc2[mt][nt], 0, 0, 0);
  }

  // ---- epilogue: write updated_ef + atomic scatter-add into agg[dst] ----
#pragma unroll
  for (int mt = 0; mt < 4; mt++) {
#pragma unroll
    for (int r = 0; r < 4; r++) {
      int row = mt * 16 + q * 4 + r;
      int e = e0 + row;
      int d = dst[e];
#pragma unroll
      for (int nt = 0; nt < 2; nt++) {
        int col = nb2 + nt * 16 + ln15;
        float v = acc2[mt][nt][r] + bias2[nt];
        out_ef[(size_t)e * 128 + col] = v;
        atomicAdd(&agg[(size_t)d * 128 + col], v);
      }
    }
  }
}

// ---------------- node kernel: 64 nodes/block, fused 2-layer MLP ----------------
__global__ __launch_bounds__(256, 3) void node_kernel(
    const float* __restrict__ agg, const unsigned short* __restrict__ nf_bf,
    const unsigned short* __restrict__ Wn1T, const float* __restrict__ bn1,
    const unsigned short* __restrict__ Wn2T, const float* __restrict__ bn2,
    float* __restrict__ out_nf) {
  __shared__ unsigned short smem[64 * HS];   // 33792 B; h overlaid after barrier

  const int tid  = threadIdx.x;
  const int lane = tid & 63;
  const int wave = tid >> 6;
  const int ln15 = lane & 15;
  const int q    = lane >> 4;
  const int n0   = blockIdx.x * 64;

  // ---- stage nm_in = [agg | nf] as bf16 ----
  {
    const float4* agg4 = (const float4*)agg;
#pragma unroll
    for (int i = 0; i < 8; i++) {
      int flat = tid + 256 * i;
      int row = flat >> 5, c4 = flat & 31;
      int node = n0 + row;
      float4 v = make_float4(0.f, 0.f, 0.f, 0.f);
      if (node < N_NODES) v = agg4[(size_t)node * 32 + c4];
      ushort4 o = { f2bf(v.x), f2bf(v.y), f2bf(v.z), f2bf(v.w) };
      *(ushort4*)&smem[row * HS + c4 * 4] = o;
    }
#pragma unroll
    for (int i = 0; i < 4; i++) {
      int flat = tid + 256 * i;
      int row = flat >> 4, seg = flat & 15;
      int node = n0 + row;
      uint4 v = make_uint4(0u, 0u, 0u, 0u);
      if (node < N_NODES) v = *(const uint4*)&nf_bf[(size_t)node * 128 + seg * 8];
      *(uint4*)&smem[row * HS + 128 + seg * 8] = v;
    }
  }
  __syncthreads();

  // ---- layer 1: K=256 ----
  const int nb1 = wave * 64;
  f32x4 acc[4][4] = {};
  float bias1[4];
#pragma unroll
  for (int nt = 0; nt < 4; nt++) bias1[nt] = bn1[nb1 + nt * 16 + ln15];

#pragma unroll
  for (int ks = 0; ks < 8; ks++) {
    const int kc = ks * 32 + q * 8;
    bf16x8 a[4], b[4];
#pragma unroll
    for (int mt = 0; mt < 4; mt++)
      a[mt] = *(const bf16x8*)&smem[(mt * 16 + ln15) * HS + kc];
#pragma unroll
    for (int nt = 0; nt < 4; nt++)
      b[nt] = *(const bf16x8*)&Wn1T[(size_t)(nb1 + nt * 16 + ln15) * 256 + kc];
#pragma unroll
    for (int mt = 0; mt < 4; mt++)
#pragma unroll
      for (int nt = 0; nt < 4; nt++)
        acc[mt][nt] = __builtin_amdgcn_mfma_f32_16x16x32_bf16(a[mt], b[nt], acc[mt][nt], 0, 0, 0);
  }
  __syncthreads();

#pragma unroll
  for (int mt = 0; mt < 4; mt++)
#pragma unroll
    for (int nt = 0; nt < 4; nt++)
#pragma unroll
      for (int r = 0; r < 4; r++) {
        float v = acc[mt][nt][r] + bias1[nt];
        v = v > 0.f ? v : 0.f;
        smem[(mt * 16 + q * 4 + r) * HS + nb1 + nt * 16 + ln15] = f2bf(v);
      }
  __syncthreads();

  // ---- layer 2: K=256, N=128 ----
  const int nb2 = wave * 32;
  f32x4 acc2[4][2] = {};
  float bias2[2];
#pragma unroll
  for (int nt = 0; nt < 2; nt++) bias2[nt] = bn2[nb2 + nt * 16 + ln15];

#pragma unroll
  for (int ks = 0; ks < 8; ks++) {
    const int kc = ks * 32 + q * 8;
    bf16x8 a2[4], b2[2];
#pragma unroll
    for (int mt = 0; mt < 4; mt++)
      a2[mt] = *(const bf16x8*)&smem[(mt * 16 + ln15) * HS + kc];
#pragma unroll
    for (int nt = 0; nt < 2; nt++)
      b2[nt] = *(const bf16x8*)&Wn2T[(size_t)(nb2 + nt * 16 + ln15) * 256 + kc];
#pragma unroll
    for (int mt = 0; mt < 4; mt++)
#pragma unroll
      for (int nt = 0; nt < 2; nt++)
        acc2[mt][nt] = __builtin_amdgcn_mfma_f32_16x16x32_bf16(a2[mt], b2[nt], acc2[mt][nt], 0, 0, 0);
  }

#pragma unroll
  for (int mt = 0; mt < 4; mt++) {
#pragma unroll
    for (int r = 0; r < 4; r++) {
      int row = mt * 16 + q * 4 + r;
      int node = n0 + row;
      if (node < N_NODES) {
#pragma unroll
        for (int nt = 0; nt < 2; nt++) {
          int col = nb2 + nt * 16 + ln15;
          out_nf[(size_t)node * 128 + col] = acc2[mt][nt][r] + bias2[nt];
        }
      }
    }
  }
}

extern "C" void kernel_launch(void* const* d_in, const int* in_sizes, int n_in,
                              void* d_out, int out_size, void* d_ws, size_t ws_size,
                              hipStream_t stream) {
  const float* nf  = (const float*)d_in[0];
  const float* ef  = (const float*)d_in[1];
  const int*   src = (const int*)d_in[2];
  const int*   dst = (const int*)d_in[3];
  const float* We1 = (const float*)d_in[4];
  const float* be1 = (const float*)d_in[5];
  const float* We2 = (const float*)d_in[6];
  const float* be2 = (const float*)d_in[7];
  const float* Wn1 = (const float*)d_in[8];
  const float* bn1 = (const float*)d_in[9];
  const float* Wn2 = (const float*)d_in[10];
  const float* bn2 = (const float*)d_in[11];

  float* out_nf = (float*)d_out;                    // updated_nf first (return order)
  float* out_ef = out_nf + (size_t)N_NODES * D;     // then updated_ef

  char* ws = (char*)d_ws;
  float*          agg   = (float*)ws;                          // 10,240,000 B
  unsigned short* nf_bf = (unsigned short*)(ws + 10240000);    //  5,120,000 B
  unsigned short* We1T  = (unsigned short*)(ws + 15360000);    //    196,608 B
  unsigned short* We2T  = (unsigned short*)(ws + 15556608);    //     65,536 B
  unsigned short* Wn1T  = (unsigned short*)(ws + 15622144);    //    131,072 B
  unsigned short* Wn2T  = (unsigned short*)(ws + 15753216);    //     65,536 B

  prep_kernel<<<10000, 256, 0, stream>>>(nf, We1, We2, Wn1, Wn2,
                                         agg, nf_bf, We1T, We2T, Wn1T, Wn2T);
  edge_kernel<<<N_EDGES / 64, 256, 0, stream>>>(ef, nf_bf, src, dst,
                                                We1T, be1, We2T, be2, out_ef, agg);
  node_kernel<<<(N_NODES + 63) / 64, 256, 0, stream>>>(agg, nf_bf,
                                                       Wn1T, bn1, Wn2T, bn2, out_nf);
}